// Round 3
// baseline (372.064 us; speedup 1.0000x reference)
//
#include <hip/hip_runtime.h>
#include <hip/hip_bf16.h>

// Problem constants: B=2, S=2048, HID=2048, H=16, HD=128, HD2=64, LAT=256
#define BB 2
#define SS 2048
#define HID 2048
#define NH 16
#define BS (BB*SS)          // 4096 rows
#define SCALE 0.088388347648318447f   // 1/sqrt(128)
#define C2LOG 0.12751743f              // SCALE * log2(e)

typedef __bf16 bf16x8 __attribute__((ext_vector_type(8)));
typedef float f32x4 __attribute__((ext_vector_type(4)));
typedef float f32x16 __attribute__((ext_vector_type(16)));
typedef unsigned int uintx2 __attribute__((ext_vector_type(2)));

__device__ __forceinline__ bf16x8 ld_frag(const __hip_bfloat16* p) {
    uint4 u = *reinterpret_cast<const uint4*>(p);
    return __builtin_bit_cast(bf16x8, u);
}
__device__ __forceinline__ void store_c(__hip_bfloat16* C, size_t idx, float v) {
    C[idx] = __float2bfloat16(v);
}
__device__ __forceinline__ void store_c(float* C, size_t idx, float v) {
    C[idx] = v;
}
__device__ __forceinline__ ushort bf_bits(float v) {
    __hip_bfloat16 h = __float2bfloat16(v);
    return *reinterpret_cast<ushort*>(&h);
}

// async global->LDS, 16B per lane; lds addr must be wave-uniform base + lane*16
#define GLD16(gp, lp) \
  __builtin_amdgcn_global_load_lds((const __attribute__((address_space(1))) void*)(gp), \
                                   (__attribute__((address_space(3))) void*)(lp), 16, 0, 0)

// ---------------------------------------------------------------------------
// fp32 -> bf16 flat convert (hs)
// ---------------------------------------------------------------------------
__global__ __launch_bounds__(256) void convert_kernel(
    const float* __restrict__ src, __hip_bfloat16* __restrict__ dst, int n8)
{
    int i = blockIdx.x * blockDim.x + threadIdx.x;
    if (i >= n8) return;
    float4 a = reinterpret_cast<const float4*>(src)[2 * i];
    float4 b = reinterpret_cast<const float4*>(src)[2 * i + 1];
    ushort u[8] = { bf_bits(a.x), bf_bits(a.y), bf_bits(a.z), bf_bits(a.w),
                    bf_bits(b.x), bf_bits(b.y), bf_bits(b.z), bf_bits(b.w) };
    reinterpret_cast<uint4*>(dst)[i] = *reinterpret_cast<uint4*>(u);
}

// ---------------------------------------------------------------------------
// Fused weight transpose+convert: 8 segments, src fp32 [R][C] -> dst bf16 [C][R]
// ---------------------------------------------------------------------------
__global__ __launch_bounds__(256) void transpose_weights_kernel(
    const float* s0, const float* s1, const float* s2, const float* s3,
    const float* s4, const float* s5, const float* s6, const float* s7,
    __hip_bfloat16* WT1, __hip_bfloat16* WT2, __hip_bfloat16* WT3,
    __hip_bfloat16* WTo)
{
    const float* srcs[8] = { s0, s1, s2, s3, s4, s5, s6, s7 };
    const int Rs[8] = { 2048, 2048, 2048, 256, 256, 256, 256, 2048 };
    const int Cs[8] = { 256, 256, 1024, 1024, 2048, 1024, 1024, 2048 };
    __hip_bfloat16* dsts[8] = {
        WT1, WT1 + (size_t)256 * 2048, WT1 + (size_t)512 * 2048,
        WT2, WT2 + (size_t)1024 * 256,
        WT3, WT3 + (size_t)1024 * 256,
        WTo };
    const int prefix[9] = { 0, 512, 1024, 3072, 3328, 3840, 4096, 4352, 8448 };

    int bid = blockIdx.x;
    int seg = 0;
    #pragma unroll
    for (int i = 0; i < 8; i++) if (bid >= prefix[i + 1]) seg = i + 1;
    int local = bid - prefix[seg];
    int R = Rs[seg], C = Cs[seg];
    int tilesC = C / 32;
    int tr = local / tilesC, tc = local % tilesC;
    int r0 = tr * 32, c0 = tc * 32;
    const float* src = srcs[seg];
    __hip_bfloat16* dst = dsts[seg];

    __shared__ float Ts[32][33];
    int t = threadIdx.x;
    int ty = t >> 5, tx = t & 31;
    #pragma unroll
    for (int k = 0; k < 4; k++) {
        int r = ty + k * 8;
        Ts[r][tx] = src[(size_t)(r0 + r) * C + c0 + tx];
    }
    __syncthreads();
    #pragma unroll
    for (int k = 0; k < 4; k++) {
        int r = ty + k * 8;
        dst[(size_t)(c0 + r) * R + r0 + tx] = __float2bfloat16(Ts[tx][r]);
    }
}

// ---------------------------------------------------------------------------
// m97-style GEMM: C = A[M,K] * Bt[N,K]^T, bf16 in, fp32 acc.
// 128x128 tile, BK=32, global_load_lds staging, 4 waves each 64x64.
// Epilogue routing: col < splitN -> (C0,...) else (C1,...). cm = output scale.
//   s64==0: plain col;  s64==1: col c -> (c>>6)*128 + (c&63) + off (head scatter)
//   s64==2: transposed store: Cp[(size_t)c*4096 + row]  (V-transpose for flash)
// ---------------------------------------------------------------------------
template <typename TC>
__global__ __launch_bounds__(256) void gemm_bt_kernel(
    const __hip_bfloat16* __restrict__ A, int lda,
    const __hip_bfloat16* __restrict__ Bt,
    TC* __restrict__ C0, int ldc0, int sp0, int off0, float cm0,
    TC* __restrict__ C1, int ldc1, int sp1, int off1, float cm1,
    int splitN, int K)
{
    __shared__ alignas(16) __hip_bfloat16 As[128 * 32];
    __shared__ alignas(16) __hip_bfloat16 Bs[128 * 32];

    const int bn = blockIdx.x * 128;
    const int bm = blockIdx.y * 128;
    const int t = threadIdx.x;
    const int w = t >> 6;
    const int lane = t & 63;
    const int l15 = lane & 15;
    const int quad = lane >> 4;
    const int wm = (w & 1) * 64;
    const int wn = (w >> 1) * 64;

    const int srow = lane >> 2;          // 0..15
    const int skcol = (lane & 3) * 8;    // 0,8,16,24

    f32x4 acc[4][4] = {};

    for (int k0 = 0; k0 < K; k0 += 32) {
        __syncthreads();
        #pragma unroll
        for (int i = 0; i < 2; i++) {
            int r = w * 32 + i * 16 + srow;
            GLD16(A + (size_t)(bm + r) * lda + k0 + skcol, &As[r * 32 + skcol]);
            GLD16(Bt + (size_t)(bn + r) * K + k0 + skcol, &Bs[r * 32 + skcol]);
        }
        __syncthreads();

        bf16x8 af[4], bf[4];
        #pragma unroll
        for (int mt = 0; mt < 4; mt++)
            af[mt] = ld_frag(&As[(wm + mt * 16 + l15) * 32 + quad * 8]);
        #pragma unroll
        for (int nt = 0; nt < 4; nt++)
            bf[nt] = ld_frag(&Bs[(wn + nt * 16 + l15) * 32 + quad * 8]);
        #pragma unroll
        for (int mt = 0; mt < 4; mt++)
            #pragma unroll
            for (int nt = 0; nt < 4; nt++)
                acc[mt][nt] = __builtin_amdgcn_mfma_f32_16x16x32_bf16(
                    af[mt], bf[nt], acc[mt][nt], 0, 0, 0);
    }

    #pragma unroll
    for (int nt = 0; nt < 4; nt++) {
        int col = bn + wn + nt * 16 + l15;
        TC* Cp; int c, ld, s64, off; float cm;
        if (col < splitN) { Cp = C0; c = col; ld = ldc0; s64 = sp0; off = off0; cm = cm0; }
        else { Cp = C1; c = col - splitN; ld = ldc1; s64 = sp1; off = off1; cm = cm1; }
        if (s64 == 2) {
            #pragma unroll
            for (int mt = 0; mt < 4; mt++) {
                int row0 = bm + wm + mt * 16 + quad * 4;
                #pragma unroll
                for (int r = 0; r < 4; r++)
                    store_c(Cp, (size_t)c * 4096 + row0 + r, acc[mt][nt][r] * cm);
            }
        } else {
            int oc = s64 ? ((c >> 6) * 128 + (c & 63) + off) : c;
            #pragma unroll
            for (int mt = 0; mt < 4; mt++) {
                #pragma unroll
                for (int r = 0; r < 4; r++) {
                    int row = bm + wm + mt * 16 + quad * 4 + r;
                    store_c(Cp, (size_t)row * ld + oc, acc[mt][nt][r] * cm);
                }
            }
        }
    }
}

// ---------------------------------------------------------------------------
// RoPE in-place on K/Q rope halves: cols h*128+64+i and h*128+96+i rotated.
// ---------------------------------------------------------------------------
__global__ __launch_bounds__(256) void rope_kernel(
    __hip_bfloat16* __restrict__ Kb, __hip_bfloat16* __restrict__ Qb)
{
    int idx = blockIdx.x * blockDim.x + threadIdx.x;
    if (idx >= BS * NH * 32) return;
    int i = idx & 31;
    int h = (idx >> 5) & 15;
    int row = idx >> 9;
    int s = row & (SS - 1);

    float inv = exp2f(-(float)i * 0.4152410118609203f);  // 10000^(-i/32)
    float ang = (float)s * inv;
    float sn = sinf(ang), cs = cosf(ang);

    size_t obase = (size_t)row * 2048 + h * 128 + 64 + i;
    {
        float x1 = __bfloat162float(Kb[obase]);
        float x2 = __bfloat162float(Kb[obase + 32]);
        Kb[obase]      = __float2bfloat16(x1 * cs - x2 * sn);
        Kb[obase + 32] = __float2bfloat16(x1 * sn + x2 * cs);
    }
    {
        float x1 = __bfloat162float(Qb[obase]);
        float x2 = __bfloat162float(Qb[obase + 32]);
        Qb[obase]      = __float2bfloat16(x1 * cs - x2 * sn);
        Qb[obase + 32] = __float2bfloat16(x1 * sn + x2 * cs);
    }
}

// ---------------------------------------------------------------------------
// Flash attention v10: v9 compute core, split into 2 independent blocks/CU.
// Counter evidence r2: per-iteration 7280 cyc vs identified work ~2900 VALU +
// 512 MFMA + ~1900 LDS -> ~2200 cyc barrier/lockstep stall with ONE barrier
// domain per CU (grid 256 = 1 block/CU, 8 lockstep waves).
// v10: 256-thread 4-wave blocks paired at 64-row q-tile granularity:
// block x in [0,16): waves 0-1 own big tile 31-x, waves 2-3 own small tile x.
// Uniform work: per-iter cost ~ active waves (4 early, 2 late) -> block
// duration ~ 66 units for every x. Grid 16x16x2 = 512 blocks -> 2 blocks/CU
// (LDS 48KB -> 96KB/CU), TWO independent barrier domains per CU: when block A
// drains at s_barrier/vmcnt, block B issues. Staging 4-way per wave (4 K + 4 V
// issues); vmcnt(8) = K(kt) landed, vmcnt(4) = V(kt) landed.
// Also: interior-tile mask skip (cndmask only on the 1 diagonal tile per wave
// range, wave-uniform branch) and T5 setprio(1) around MFMA clusters (two
// blocks/CU give real wave role diversity, m191-style).
// ---------------------------------------------------------------------------
__global__ __launch_bounds__(256) void flash_attn_kernel(
    const __hip_bfloat16* __restrict__ Q,
    const __hip_bfloat16* __restrict__ Kb,
    const __hip_bfloat16* __restrict__ Vt,
    __hip_bfloat16* __restrict__ O)
{
    __shared__ alignas(16) __hip_bfloat16 Ktd[2 * 4 * 64 * 32]; // dbuf K: [par][ds 4][64 kv][32 d]
    __shared__ alignas(16) __hip_bfloat16 Vs[2 * 128 * 32];     // [kvh 2][128 d][32 kv]

    const int x = blockIdx.x;            // pair index 0..15
    const int h = blockIdx.y;
    const int b = blockIdx.z;
    const int t = threadIdx.x;
    const int w = t >> 6;                // 0..3
    const int lane = t & 63;
    const int l31 = lane & 31;
    const int hi = lane >> 5;
    const int swl = (l31 >> 1) & 3;      // read-side chunk xor term

    const int qt = (w < 2) ? (31 - x) : x;   // this wave's 64-row q-tile
    const int qwb = qt * 64 + (w & 1) * 32;  // wave's q base (32 rows)
    const int q = qwb + l31;                 // this lane's q row
    const int my_nt = qt + 1;                // kv tiles this wave needs
    const int nbig = 32 - x;                 // shared loop length

    const __hip_bfloat16* Kbase = Kb + (size_t)(b * SS) * 2048 + h * 128;
    const __hip_bfloat16* Vtb = Vt + (size_t)(h * 128) * 4096 + b * SS;

    // Q B-frags: qf[s] = Q[q][d = 16s + 8hi + j], j=0..7
    bf16x8 qf[8];
    {
        const __hip_bfloat16* qrow = Q + (size_t)(b * SS + q) * 2048 + h * 128;
        #pragma unroll
        for (int s = 0; s < 8; s++)
            qf[s] = ld_frag(qrow + s * 16 + hi * 8);
    }

    const int Lr = lane >> 2;                      // row within staging issue
    const int Lc = (lane & 3) ^ ((lane >> 3) & 3); // store-side chunk swizzle

    float m_i = -INFINITY;   // running max, log2 domain (S * C2LOG)
    float l_i = 0.0f;
    f32x16 acc[4] = {};      // O^T: acc[dt], d = dt*32 + (e&3) + 8*(e>>2) + 4*hi, col q=l31

    // staging assignment (4 waves, 4 issues each per matrix):
    //   K: wave w -> ds-subtile w (d-range w*32..w*32+31), rows i*16+Lr
    //   V: wave w -> kvh = w&1, d-half = w>>1
    const int vkvh = w & 1, vdh = w >> 1;

    // prologue: stage K tile 0 into buffer 0
    #pragma unroll
    for (int i = 0; i < 4; i++)
        GLD16(Kbase + (size_t)(i * 16 + Lr) * 2048 + w * 32 + Lc * 8,
              &Ktd[w * 2048 + i * 512 + lane * 8]);
    // pin the qf waitcnt into the prologue (fake use)
    asm volatile("" :: "v"(qf[0]), "v"(qf[1]), "v"(qf[2]), "v"(qf[3]),
                       "v"(qf[4]), "v"(qf[5]), "v"(qf[6]), "v"(qf[7]));

    for (int kt = 0; kt < nbig; kt++) {
        const int kvb = kt * 64;
        const int par = kt & 1;
        const bool active = (kt < my_nt);

        __builtin_amdgcn_s_barrier();              // A: prev tile's PV done
        asm volatile("" ::: "memory");

        // ---- stage V(kt) ----
        #pragma unroll
        for (int i = 0; i < 4; i++)
            GLD16(Vtb + (size_t)(vdh * 64 + i * 16 + Lr) * 4096
                      + kvb + vkvh * 32 + Lc * 8,
                  &Vs[vkvh * 4096 + vdh * 2048 + i * 512 + lane * 8]);
        // ---- stage K(kt+1) into other parity (clamped on last tile) ----
        {
            const int kvb1 = ((kt + 1 < nbig) ? kt + 1 : nbig - 1) * 64;
            __hip_bfloat16* kdst = &Ktd[((kt + 1) & 1) * 8192 + w * 2048];
            #pragma unroll
            for (int i = 0; i < 4; i++)
                GLD16(Kbase + (size_t)(kvb1 + i * 16 + Lr) * 2048 + w * 32 + Lc * 8,
                      kdst + i * 512 + lane * 8);
        }
        asm volatile("s_waitcnt vmcnt(8)" ::: "memory");  // K(kt) landed
        __builtin_amdgcn_s_barrier();              // B: K(kt) visible to all waves
        asm volatile("" ::: "memory");

        uint4 af[4];
        if (active) {
            // ---- S^T = K * Q^T : 2 kv-blocks x 8 k-steps of 32x32x16 ----
            const __hip_bfloat16* kb_base = &Ktd[par * 8192];
            f32x16 st[2] = {};
            __builtin_amdgcn_s_setprio(1);
            #pragma unroll
            for (int s = 0; s < 8; s++)
                #pragma unroll
                for (int kb = 0; kb < 2; kb++) {
                    bf16x8 kf = ld_frag(kb_base + (s >> 1) * 2048 + (kb * 32 + l31) * 32
                                        + ((2 * (s & 1) + hi) ^ swl) * 8);
                    st[kb] = __builtin_amdgcn_mfma_f32_32x32x16_bf16(
                        kf, qf[s], st[kb], 0, 0, 0);
                }
            __builtin_amdgcn_s_setprio(0);

            // ---- row max; causal cndmask only on the diagonal tile ----
            float tmx = -INFINITY;
            if (kvb + 63 > qwb) {            // wave-uniform: diagonal tile
                const int thr = q - kvb - 4 * hi;   // pass iff kb*32 + 8g + r <= thr
                #pragma unroll
                for (int kb = 0; kb < 2; kb++)
                    #pragma unroll
                    for (int g = 0; g < 4; g++)
                        #pragma unroll
                        for (int r = 0; r < 4; r++) {
                            const int e = g * 4 + r;
                            float v = (kb * 32 + 8 * g + r <= thr) ? st[kb][e] : -INFINITY;
                            st[kb][e] = v;
                            tmx = fmaxf(tmx, v);
                        }
            } else {                          // interior: no masking needed
                #pragma unroll
                for (int kb = 0; kb < 2; kb++)
                    #pragma unroll
                    for (int e = 0; e < 16; e++)
                        tmx = fmaxf(tmx, st[kb][e]);
            }
            tmx = fmaxf(tmx, __shfl_xor(tmx, 32));
            const float m2x = tmx * C2LOG;

            // ---- online softmax (log2 domain) + T13 defer-max ----
            const bool nosc = __all(m2x <= m_i + 8.0f);
            const float mnew = nosc ? m_i : fmaxf(m_i, m2x);
            float rs = 0.0f;
            #pragma unroll
            for (int kb = 0; kb < 2; kb++)
                #pragma unroll
                for (int e = 0; e < 16; e++) {
                    float pv = exp2f(fmaf(st[kb][e], C2LOG, -mnew));
                    st[kb][e] = pv;
                    rs += pv;
                }
            rs += __shfl_xor(rs, 32);
            if (!nosc) {
                const float alpha = exp2f(m_i - mnew);
                m_i = mnew;
                l_i *= alpha;
                #pragma unroll
                for (int dt = 0; dt < 4; dt++)
                    #pragma unroll
                    for (int e = 0; e < 16; e++)
                        acc[dt][e] *= alpha;
            }
            l_i += rs;

            // ---- P -> bf16 PV B-frags entirely in registers (T12) ----
            #pragma unroll
            for (int kb = 0; kb < 2; kb++) {
                unsigned int pk[4][2];
                #pragma unroll
                for (int g = 0; g < 4; g++)
                    #pragma unroll
                    for (int i = 0; i < 2; i++) {
                        float2 fp = make_float2(st[kb][g * 4 + 2 * i],
                                                st[kb][g * 4 + 2 * i + 1]);
                        __hip_bfloat162 h2 = __float22bfloat162_rn(fp);
                        pk[g][i] = *reinterpret_cast<unsigned int*>(&h2);
                    }
                #pragma unroll
                for (int sl = 0; sl < 2; sl++) {
                    uintx2 r0 = __builtin_amdgcn_permlane32_swap(
                        pk[2 * sl][0], pk[2 * sl + 1][0], false, false);
                    uintx2 r1 = __builtin_amdgcn_permlane32_swap(
                        pk[2 * sl][1], pk[2 * sl + 1][1], false, false);
                    af[kb * 2 + sl] = make_uint4(r0[0], r1[0], r0[1], r1[1]);
                }
            }
        }

        asm volatile("s_waitcnt vmcnt(4)" ::: "memory");  // V(kt) landed; K(kt+1) in flight
        __builtin_amdgcn_s_barrier();              // C: V(kt) visible to all waves
        asm volatile("" ::: "memory");

        if (active) {
            // ---- O^T += V^T * P^T : 4 d-tiles x 4 kv-steps ----
            __builtin_amdgcn_s_setprio(1);
            #pragma unroll
            for (int s = 0; s < 4; s++) {
                bf16x8 pf = __builtin_bit_cast(bf16x8, af[s]);
                #pragma unroll
                for (int dt = 0; dt < 4; dt++) {
                    bf16x8 vf = ld_frag(&Vs[(s >> 1) * 4096 + (dt * 32 + l31) * 32
                                            + ((2 * (s & 1) + hi) ^ swl) * 8]);
                    acc[dt] = __builtin_amdgcn_mfma_f32_32x32x16_bf16(
                        vf, pf, acc[dt], 0, 0, 0);
                }
            }
            __builtin_amdgcn_s_setprio(0);
        }
    }

    // ---- epilogue: per-lane q = l31, d = dt*32 + 8g + 4hi + r ----
    const float inv_l = 1.0f / l_i;
    __hip_bfloat16* orow = O + (size_t)(b * SS + q) * 2048 + h * 128;
    #pragma unroll
    for (int dt = 0; dt < 4; dt++)
        #pragma unroll
        for (int g = 0; g < 4; g++) {
            ushort u[4];
            #pragma unroll
            for (int r = 0; r < 4; r++)
                u[r] = bf_bits(acc[dt][g * 4 + r] * inv_l);
            *reinterpret_cast<uint2*>(orow + dt * 32 + 8 * g + 4 * hi) =
                *reinterpret_cast<uint2*>(u);
        }
}

// ---------------------------------------------------------------------------
extern "C" void kernel_launch(void* const* d_in, const int* in_sizes, int n_in,
                              void* d_out, int out_size, void* d_ws, size_t ws_size,
                              hipStream_t stream)
{
    const float* hs       = (const float*)d_in[0];
    const float* w_kv_d   = (const float*)d_in[1];
    const float* w_q_d    = (const float*)d_in[2];
    const float* w_k_u    = (const float*)d_in[3];
    const float* w_q_u    = (const float*)d_in[4];
    const float* w_v_u    = (const float*)d_in[5];
    const float* w_rope_k = (const float*)d_in[6];
    const float* w_rope_q = (const float*)d_in[7];
    const float* w_o      = (const float*)d_in[8];
    float* out = (float*)d_out;

    char* p = (char*)d_ws;
    auto alloc = [&](size_t nelem) {
        __hip_bfloat16* r = (__hip_bfloat16*)p;
        p += nelem * sizeof(__hip_bfloat16);
        return r;
    };
    __hip_bfloat16* hsb  = alloc((size_t)BS * HID);        // 16 MB (reused as attn)
    __hip_bfloat16* qkvd = alloc((size_t)BS * 512);        // 4 MB
    __hip_bfloat16* WT1  = alloc((size_t)1536 * 2048);     // 6 MB
    __hip_bfloat16* WT2  = alloc((size_t)3072 * 256);      // 1.5 MB
    __hip_bfloat16* WT3  = alloc((size_t)2048 * 256);      // 1 MB
    __hip_bfloat16* WTo  = alloc((size_t)2048 * 2048);     // 8 MB
    __hip_bfloat16* Kbuf = alloc((size_t)BS * HID);        // 16 MB
    __hip_bfloat16* Qbuf = alloc((size_t)BS * HID);        // 16 MB
    __hip_bfloat16* Vtb  = alloc((size_t)HID * BS);        // 16 MB, [h*128+d][b*S+s]
    __hip_bfloat16* attn = hsb;   // hs dead after G1

    dim3 blk(256);

    // 0a. hs -> bf16
    convert_kernel<<<dim3((BS * HID / 8 + 255) / 256), blk, 0, stream>>>(
        hs, hsb, BS * HID / 8);
    // 0b. all weights: transpose + convert to bf16 W^T
    transpose_weights_kernel<<<dim3(8448), blk, 0, stream>>>(
        w_kv_d, w_q_d, w_rope_k, w_k_u, w_v_u, w_q_u, w_rope_q, w_o,
        WT1, WT2, WT3, WTo);

    // G1: [kv_d | q_d | krp] = hsb @ WT1^T  (N=1536, K=2048)
    gemm_bt_kernel<__hip_bfloat16><<<dim3(1536 / 128, BS / 128), blk, 0, stream>>>(
        hsb, 2048, WT1,
        qkvd, 512, 0, 0, 1.0f,
        Kbuf, 2048, 1, 64, 1.0f,
        512, 2048);
    // G2: [k_p | v] = kv_d @ WT2^T  (N=3072, K=256)
    gemm_bt_kernel<__hip_bfloat16><<<dim3(3072 / 128, BS / 128), blk, 0, stream>>>(
        qkvd, 512, WT2,
        Kbuf, 2048, 1, 0, 1.0f,
        Vtb, 0, 2, 0, 1.0f,
        1024, 256);
    // G3: [q_p | q_rope_pre] = q_d @ WT3^T  (N=2048, K=256)
    gemm_bt_kernel<__hip_bfloat16><<<dim3(2048 / 128, BS / 128), blk, 0, stream>>>(
        qkvd + 256, 512, WT3,
        Qbuf, 2048, 1, 0, 1.0f,
        Qbuf, 2048, 1, 64, 1.0f,
        1024, 256);
    // 4. RoPE in-place on K/Q rope halves
    rope_kernel<<<dim3((BS * NH * 32 + 255) / 256), blk, 0, stream>>>(Kbuf, Qbuf);
    // 5. flash attention v10 -> attn (4-wave paired blocks, 2 blocks/CU)
    flash_attn_kernel<<<dim3(16, NH, BB), dim3(256), 0, stream>>>(
        Qbuf, Kbuf, Vtb, attn);
    // G4: out = attn @ WTo^T (fp32 out)
    gemm_bt_kernel<float><<<dim3(2048 / 128, BS / 128), blk, 0, stream>>>(
        attn, 2048, WTo,
        out, 2048, 0, 0, 1.0f,
        out, 2048, 0, 0, 1.0f,
        2048, 2048);
}

// Round 4
// 347.645 us; speedup vs baseline: 1.0702x; 1.0702x over previous
//
#include <hip/hip_runtime.h>
#include <hip/hip_bf16.h>

// Problem constants: B=2, S=2048, HID=2048, H=16, HD=128, HD2=64, LAT=256
#define BB 2
#define SS 2048
#define HID 2048
#define NH 16
#define BS (BB*SS)          // 4096 rows
#define SCALE 0.088388347648318447f   // 1/sqrt(128)
#define C2LOG 0.12751743f              // SCALE * log2(e)

typedef __bf16 bf16x8 __attribute__((ext_vector_type(8)));
typedef float f32x4 __attribute__((ext_vector_type(4)));
typedef float f32x16 __attribute__((ext_vector_type(16)));
typedef unsigned int uintx2 __attribute__((ext_vector_type(2)));

__device__ __forceinline__ bf16x8 ld_frag(const __hip_bfloat16* p) {
    uint4 u = *reinterpret_cast<const uint4*>(p);
    return __builtin_bit_cast(bf16x8, u);
}
__device__ __forceinline__ void store_c(__hip_bfloat16* C, size_t idx, float v) {
    C[idx] = __float2bfloat16(v);
}
__device__ __forceinline__ void store_c(float* C, size_t idx, float v) {
    C[idx] = v;
}
__device__ __forceinline__ ushort bf_bits(float v) {
    __hip_bfloat16 h = __float2bfloat16(v);
    return *reinterpret_cast<ushort*>(&h);
}

// async global->LDS, 16B per lane; lds addr must be wave-uniform base + lane*16
#define GLD16(gp, lp) \
  __builtin_amdgcn_global_load_lds((const __attribute__((address_space(1))) void*)(gp), \
                                   (__attribute__((address_space(3))) void*)(lp), 16, 0, 0)

// ---------------------------------------------------------------------------
// fp32 -> bf16 flat convert (hs)
// ---------------------------------------------------------------------------
__global__ __launch_bounds__(256) void convert_kernel(
    const float* __restrict__ src, __hip_bfloat16* __restrict__ dst, int n8)
{
    int i = blockIdx.x * blockDim.x + threadIdx.x;
    if (i >= n8) return;
    float4 a = reinterpret_cast<const float4*>(src)[2 * i];
    float4 b = reinterpret_cast<const float4*>(src)[2 * i + 1];
    ushort u[8] = { bf_bits(a.x), bf_bits(a.y), bf_bits(a.z), bf_bits(a.w),
                    bf_bits(b.x), bf_bits(b.y), bf_bits(b.z), bf_bits(b.w) };
    reinterpret_cast<uint4*>(dst)[i] = *reinterpret_cast<uint4*>(u);
}

// ---------------------------------------------------------------------------
// Fused weight transpose+convert: 8 segments, src fp32 [R][C] -> dst bf16 [C][R]
// ---------------------------------------------------------------------------
__global__ __launch_bounds__(256) void transpose_weights_kernel(
    const float* s0, const float* s1, const float* s2, const float* s3,
    const float* s4, const float* s5, const float* s6, const float* s7,
    __hip_bfloat16* WT1, __hip_bfloat16* WT2, __hip_bfloat16* WT3,
    __hip_bfloat16* WTo)
{
    const float* srcs[8] = { s0, s1, s2, s3, s4, s5, s6, s7 };
    const int Rs[8] = { 2048, 2048, 2048, 256, 256, 256, 256, 2048 };
    const int Cs[8] = { 256, 256, 1024, 1024, 2048, 1024, 1024, 2048 };
    __hip_bfloat16* dsts[8] = {
        WT1, WT1 + (size_t)256 * 2048, WT1 + (size_t)512 * 2048,
        WT2, WT2 + (size_t)1024 * 256,
        WT3, WT3 + (size_t)1024 * 256,
        WTo };
    const int prefix[9] = { 0, 512, 1024, 3072, 3328, 3840, 4096, 4352, 8448 };

    int bid = blockIdx.x;
    int seg = 0;
    #pragma unroll
    for (int i = 0; i < 8; i++) if (bid >= prefix[i + 1]) seg = i + 1;
    int local = bid - prefix[seg];
    int R = Rs[seg], C = Cs[seg];
    int tilesC = C / 32;
    int tr = local / tilesC, tc = local % tilesC;
    int r0 = tr * 32, c0 = tc * 32;
    const float* src = srcs[seg];
    __hip_bfloat16* dst = dsts[seg];

    __shared__ float Ts[32][33];
    int t = threadIdx.x;
    int ty = t >> 5, tx = t & 31;
    #pragma unroll
    for (int k = 0; k < 4; k++) {
        int r = ty + k * 8;
        Ts[r][tx] = src[(size_t)(r0 + r) * C + c0 + tx];
    }
    __syncthreads();
    #pragma unroll
    for (int k = 0; k < 4; k++) {
        int r = ty + k * 8;
        dst[(size_t)(c0 + r) * R + r0 + tx] = __float2bfloat16(Ts[tx][r]);
    }
}

// ---------------------------------------------------------------------------
// m97-style GEMM: C = A[M,K] * Bt[N,K]^T, bf16 in, fp32 acc.
// 128x128 tile, BK=32, global_load_lds staging, 4 waves each 64x64.
// Epilogue routing: col < splitN -> (C0,...) else (C1,...). cm = output scale.
//   s64==0: plain col;  s64==1: col c -> (c>>6)*128 + (c&63) + off (head scatter)
//   s64==2: transposed store: Cp[(size_t)c*4096 + row]  (V-transpose for flash)
// ---------------------------------------------------------------------------
template <typename TC>
__global__ __launch_bounds__(256) void gemm_bt_kernel(
    const __hip_bfloat16* __restrict__ A, int lda,
    const __hip_bfloat16* __restrict__ Bt,
    TC* __restrict__ C0, int ldc0, int sp0, int off0, float cm0,
    TC* __restrict__ C1, int ldc1, int sp1, int off1, float cm1,
    int splitN, int K)
{
    __shared__ alignas(16) __hip_bfloat16 As[128 * 32];
    __shared__ alignas(16) __hip_bfloat16 Bs[128 * 32];

    const int bn = blockIdx.x * 128;
    const int bm = blockIdx.y * 128;
    const int t = threadIdx.x;
    const int w = t >> 6;
    const int lane = t & 63;
    const int l15 = lane & 15;
    const int quad = lane >> 4;
    const int wm = (w & 1) * 64;
    const int wn = (w >> 1) * 64;

    const int srow = lane >> 2;          // 0..15
    const int skcol = (lane & 3) * 8;    // 0,8,16,24

    f32x4 acc[4][4] = {};

    for (int k0 = 0; k0 < K; k0 += 32) {
        __syncthreads();
        #pragma unroll
        for (int i = 0; i < 2; i++) {
            int r = w * 32 + i * 16 + srow;
            GLD16(A + (size_t)(bm + r) * lda + k0 + skcol, &As[r * 32 + skcol]);
            GLD16(Bt + (size_t)(bn + r) * K + k0 + skcol, &Bs[r * 32 + skcol]);
        }
        __syncthreads();

        bf16x8 af[4], bf[4];
        #pragma unroll
        for (int mt = 0; mt < 4; mt++)
            af[mt] = ld_frag(&As[(wm + mt * 16 + l15) * 32 + quad * 8]);
        #pragma unroll
        for (int nt = 0; nt < 4; nt++)
            bf[nt] = ld_frag(&Bs[(wn + nt * 16 + l15) * 32 + quad * 8]);
        #pragma unroll
        for (int mt = 0; mt < 4; mt++)
            #pragma unroll
            for (int nt = 0; nt < 4; nt++)
                acc[mt][nt] = __builtin_amdgcn_mfma_f32_16x16x32_bf16(
                    af[mt], bf[nt], acc[mt][nt], 0, 0, 0);
    }

    #pragma unroll
    for (int nt = 0; nt < 4; nt++) {
        int col = bn + wn + nt * 16 + l15;
        TC* Cp; int c, ld, s64, off; float cm;
        if (col < splitN) { Cp = C0; c = col; ld = ldc0; s64 = sp0; off = off0; cm = cm0; }
        else { Cp = C1; c = col - splitN; ld = ldc1; s64 = sp1; off = off1; cm = cm1; }
        if (s64 == 2) {
            #pragma unroll
            for (int mt = 0; mt < 4; mt++) {
                int row0 = bm + wm + mt * 16 + quad * 4;
                #pragma unroll
                for (int r = 0; r < 4; r++)
                    store_c(Cp, (size_t)c * 4096 + row0 + r, acc[mt][nt][r] * cm);
            }
        } else {
            int oc = s64 ? ((c >> 6) * 128 + (c & 63) + off) : c;
            #pragma unroll
            for (int mt = 0; mt < 4; mt++) {
                #pragma unroll
                for (int r = 0; r < 4; r++) {
                    int row = bm + wm + mt * 16 + quad * 4 + r;
                    store_c(Cp, (size_t)row * ld + oc, acc[mt][nt][r] * cm);
                }
            }
        }
    }
}

// ---------------------------------------------------------------------------
// RoPE in-place on K/Q rope halves: cols h*128+64+i and h*128+96+i rotated.
// ---------------------------------------------------------------------------
__global__ __launch_bounds__(256) void rope_kernel(
    __hip_bfloat16* __restrict__ Kb, __hip_bfloat16* __restrict__ Qb)
{
    int idx = blockIdx.x * blockDim.x + threadIdx.x;
    if (idx >= BS * NH * 32) return;
    int i = idx & 31;
    int h = (idx >> 5) & 15;
    int row = idx >> 9;
    int s = row & (SS - 1);

    float inv = exp2f(-(float)i * 0.4152410118609203f);  // 10000^(-i/32)
    float ang = (float)s * inv;
    float sn = sinf(ang), cs = cosf(ang);

    size_t obase = (size_t)row * 2048 + h * 128 + 64 + i;
    {
        float x1 = __bfloat162float(Kb[obase]);
        float x2 = __bfloat162float(Kb[obase + 32]);
        Kb[obase]      = __float2bfloat16(x1 * cs - x2 * sn);
        Kb[obase + 32] = __float2bfloat16(x1 * sn + x2 * cs);
    }
    {
        float x1 = __bfloat162float(Qb[obase]);
        float x2 = __bfloat162float(Qb[obase + 32]);
        Qb[obase]      = __float2bfloat16(x1 * cs - x2 * sn);
        Qb[obase + 32] = __float2bfloat16(x1 * sn + x2 * cs);
    }
}

// ---------------------------------------------------------------------------
// Flash attention v11 = v9 shape (8-wave paired block, 1 block/CU, uniform
// work) + FULL K&V double-buffer.
// r3 post-mortem: v10's 2-blocks/CU split REGRESSED (96.9->109.5): doubled
// staging per CU (FETCH 110->125MB) + arbitrary long/short block pairing
// (Occupancy 18->15). Reverted.
// r2 evidence kept: v9's 7280 cyc/iter vs ~2900 VALU + ~2300 LDS + 512 MFMA
// -> ~2200 cyc barrier stall from the 3-barrier iteration where V(kt) is
// issued AND waited inside iteration kt.
// v11: both K and V double-buffered (64KB LDS). Per iteration:
//   barrier A -> issue K(kt+1)+V(kt+1) into buf[par^1] (4 GLD16/wave)
//   -> vmcnt(4) (tile kt's loads, issued a FULL iteration ago -> landed)
//   -> barrier B -> QK+softmax+pack+PV straight-line (no mid barrier).
// 3 barriers -> 2, zero-drain vmcnts, PV ds_reads overlap softmax VALU.
// Plus: interior-tile mask skip (cndmask only on each wave's 1 diagonal
// tile), per-wave my_nt = 2qt+1+(wq>>1) (drops the fully-masked tile for
// waves 0-1 of each q-tile), T5 setprio around MFMA clusters.
// ---------------------------------------------------------------------------
__global__ __launch_bounds__(512) void flash_attn_kernel(
    const __hip_bfloat16* __restrict__ Q,
    const __hip_bfloat16* __restrict__ Kb,
    const __hip_bfloat16* __restrict__ Vt,
    __hip_bfloat16* __restrict__ O)
{
    __shared__ alignas(16) __hip_bfloat16 Ktd[2 * 4 * 64 * 32];  // [par][ds4][kv64][d32]
    __shared__ alignas(16) __hip_bfloat16 Vsd[2 * 2 * 128 * 32]; // [par][kvh2][d128][kv32]

    const int p = blockIdx.x;            // pair index 0..7
    const int h = blockIdx.y;
    const int b = blockIdx.z;
    const int t = threadIdx.x;
    const int w = t >> 6;                // 0..7
    const int lane = t & 63;
    const int l31 = lane & 31;
    const int hi = lane >> 5;
    const int swl = (l31 >> 1) & 3;      // read-side chunk xor term

    const int qt = (w < 4) ? (15 - p) : p;   // this wave's q-tile
    const int wq = w & 3;
    const int qwb = qt * 128 + wq * 32;      // wave's q base (32 rows)
    const int q = qwb + l31;                 // this lane's q row
    const int my_nt = 2 * qt + 1 + (wq >> 1);// kv tiles this wave needs
    const int nbig = 2 * (15 - p) + 2;       // shared loop length

    const __hip_bfloat16* Kbase = Kb + (size_t)(b * SS) * 2048 + h * 128;
    const __hip_bfloat16* Vtb = Vt + (size_t)(h * 128) * 4096 + b * SS;

    // Q B-frags: qf[s] = Q[q][d = 16s + 8hi + j], j=0..7
    bf16x8 qf[8];
    {
        const __hip_bfloat16* qrow = Q + (size_t)(b * SS + q) * 2048 + h * 128;
        #pragma unroll
        for (int s = 0; s < 8; s++)
            qf[s] = ld_frag(qrow + s * 16 + hi * 8);
    }

    const int Lr = lane >> 2;                      // row within staging issue
    const int Lc = (lane & 3) ^ ((lane >> 3) & 3); // store-side chunk swizzle
    // staging assignment (8 waves, 2 issues each per matrix):
    //   K: wave w -> ds-subtile w>>1, kv-half w&1
    //   V: wave w -> kvh w>>2, d-quarter w&3
    const int kds = w >> 1, khalf = w & 1;
    const int vkvh = w >> 2, vdq = w & 3;

    float m_i = -INFINITY;   // running max, log2 domain (S * C2LOG)
    float l_i = 0.0f;
    f32x16 acc[4] = {};      // O^T: acc[dt], d = dt*32 + 8*(e>>2) + 4hi + (e&3), col q=l31

    // prologue: stage tile 0 (K and V) into par 0
    #pragma unroll
    for (int i = 0; i < 2; i++)
        GLD16(Kbase + (size_t)(khalf * 32 + i * 16 + Lr) * 2048 + kds * 32 + Lc * 8,
              &Ktd[kds * 2048 + khalf * 1024 + i * 512 + lane * 8]);
    #pragma unroll
    for (int i = 0; i < 2; i++)
        GLD16(Vtb + (size_t)(vdq * 32 + i * 16 + Lr) * 4096 + vkvh * 32 + Lc * 8,
              &Vsd[vkvh * 4096 + vdq * 1024 + i * 512 + lane * 8]);
    // pin the qf waitcnt into the prologue (fake use)
    asm volatile("" :: "v"(qf[0]), "v"(qf[1]), "v"(qf[2]), "v"(qf[3]),
                       "v"(qf[4]), "v"(qf[5]), "v"(qf[6]), "v"(qf[7]));

    for (int kt = 0; kt < nbig; kt++) {
        const int kvb = kt * 64;
        const int par = kt & 1;
        const bool active = (kt < my_nt);

        __builtin_amdgcn_s_barrier();              // A: all waves done reading buf[par^1]
        asm volatile("" ::: "memory");

        // ---- prefetch tile kt+1 into buf[par^1] (clamped dup on last) ----
        {
            const int kvb1 = ((kt + 1 < nbig) ? kt + 1 : kt) * 64;
            const int pn = (par ^ 1) * 8192;
            #pragma unroll
            for (int i = 0; i < 2; i++)
                GLD16(Kbase + (size_t)(kvb1 + khalf * 32 + i * 16 + Lr) * 2048
                          + kds * 32 + Lc * 8,
                      &Ktd[pn + kds * 2048 + khalf * 1024 + i * 512 + lane * 8]);
            #pragma unroll
            for (int i = 0; i < 2; i++)
                GLD16(Vtb + (size_t)(vdq * 32 + i * 16 + Lr) * 4096
                          + kvb1 + vkvh * 32 + Lc * 8,
                      &Vsd[pn + vkvh * 4096 + vdq * 1024 + i * 512 + lane * 8]);
        }
        asm volatile("s_waitcnt vmcnt(4)" ::: "memory");  // tile kt landed (own 4)
        __builtin_amdgcn_s_barrier();              // B: tile kt visible block-wide
        asm volatile("" ::: "memory");

        if (active) {
            const __hip_bfloat16* kb_base = &Ktd[par * 8192];
            const __hip_bfloat16* vb_base = &Vsd[par * 8192];

            // ---- S^T = K * Q^T : 2 kv-blocks x 8 k-steps of 32x32x16 ----
            f32x16 st[2] = {};
            __builtin_amdgcn_s_setprio(1);
            #pragma unroll
            for (int s = 0; s < 8; s++)
                #pragma unroll
                for (int kb = 0; kb < 2; kb++) {
                    bf16x8 kf = ld_frag(kb_base + (s >> 1) * 2048 + (kb * 32 + l31) * 32
                                        + ((2 * (s & 1) + hi) ^ swl) * 8);
                    st[kb] = __builtin_amdgcn_mfma_f32_32x32x16_bf16(
                        kf, qf[s], st[kb], 0, 0, 0);
                }
            __builtin_amdgcn_s_setprio(0);

            // ---- row max; causal cndmask only on the diagonal tile ----
            float tmx = -INFINITY;
            if (kvb + 63 > qwb) {            // wave-uniform: diagonal tile
                const int thr = q - kvb - 4 * hi;   // pass iff kb*32 + 8g + r <= thr
                #pragma unroll
                for (int kb = 0; kb < 2; kb++)
                    #pragma unroll
                    for (int g = 0; g < 4; g++)
                        #pragma unroll
                        for (int r = 0; r < 4; r++) {
                            const int e = g * 4 + r;
                            float v = (kb * 32 + 8 * g + r <= thr) ? st[kb][e] : -INFINITY;
                            st[kb][e] = v;
                            tmx = fmaxf(tmx, v);
                        }
            } else {                          // interior: no masking needed
                #pragma unroll
                for (int kb = 0; kb < 2; kb++)
                    #pragma unroll
                    for (int e = 0; e < 16; e++)
                        tmx = fmaxf(tmx, st[kb][e]);
            }
            tmx = fmaxf(tmx, __shfl_xor(tmx, 32));
            const float m2x = tmx * C2LOG;

            // ---- online softmax (log2 domain) + T13 defer-max ----
            const bool nosc = __all(m2x <= m_i + 8.0f);
            const float mnew = nosc ? m_i : fmaxf(m_i, m2x);
            float rs = 0.0f;
            #pragma unroll
            for (int kb = 0; kb < 2; kb++)
                #pragma unroll
                for (int e = 0; e < 16; e++) {
                    float pv = exp2f(fmaf(st[kb][e], C2LOG, -mnew));
                    st[kb][e] = pv;
                    rs += pv;
                }
            rs += __shfl_xor(rs, 32);
            if (!nosc) {
                const float alpha = exp2f(m_i - mnew);
                m_i = mnew;
                l_i *= alpha;
                #pragma unroll
                for (int dt = 0; dt < 4; dt++)
                    #pragma unroll
                    for (int e = 0; e < 16; e++)
                        acc[dt][e] *= alpha;
            }
            l_i += rs;

            // ---- P -> bf16 PV B-frags entirely in registers (T12) ----
            uint4 af[4];
            #pragma unroll
            for (int kb = 0; kb < 2; kb++) {
                unsigned int pk[4][2];
                #pragma unroll
                for (int g = 0; g < 4; g++)
                    #pragma unroll
                    for (int i = 0; i < 2; i++) {
                        float2 fp = make_float2(st[kb][g * 4 + 2 * i],
                                                st[kb][g * 4 + 2 * i + 1]);
                        __hip_bfloat162 h2 = __float22bfloat162_rn(fp);
                        pk[g][i] = *reinterpret_cast<unsigned int*>(&h2);
                    }
                #pragma unroll
                for (int sl = 0; sl < 2; sl++) {
                    uintx2 r0 = __builtin_amdgcn_permlane32_swap(
                        pk[2 * sl][0], pk[2 * sl + 1][0], false, false);
                    uintx2 r1 = __builtin_amdgcn_permlane32_swap(
                        pk[2 * sl][1], pk[2 * sl + 1][1], false, false);
                    af[kb * 2 + sl] = make_uint4(r0[0], r1[0], r0[1], r1[1]);
                }
            }

            // ---- O^T += V^T * P^T : 4 d-tiles x 4 kv-steps ----
            __builtin_amdgcn_s_setprio(1);
            #pragma unroll
            for (int s = 0; s < 4; s++) {
                bf16x8 pf = __builtin_bit_cast(bf16x8, af[s]);
                #pragma unroll
                for (int dt = 0; dt < 4; dt++) {
                    bf16x8 vf = ld_frag(vb_base + (s >> 1) * 4096 + (dt * 32 + l31) * 32
                                        + ((2 * (s & 1) + hi) ^ swl) * 8);
                    acc[dt] = __builtin_amdgcn_mfma_f32_32x32x16_bf16(
                        vf, pf, acc[dt], 0, 0, 0);
                }
            }
            __builtin_amdgcn_s_setprio(0);
        }
    }

    // ---- epilogue: per-lane q = l31, d = dt*32 + 8g + 4hi + r ----
    const float inv_l = 1.0f / l_i;
    __hip_bfloat16* orow = O + (size_t)(b * SS + q) * 2048 + h * 128;
    #pragma unroll
    for (int dt = 0; dt < 4; dt++)
        #pragma unroll
        for (int g = 0; g < 4; g++) {
            ushort u[4];
            #pragma unroll
            for (int r = 0; r < 4; r++)
                u[r] = bf_bits(acc[dt][g * 4 + r] * inv_l);
            *reinterpret_cast<uint2*>(orow + dt * 32 + 8 * g + 4 * hi) =
                *reinterpret_cast<uint2*>(u);
        }
}

// ---------------------------------------------------------------------------
extern "C" void kernel_launch(void* const* d_in, const int* in_sizes, int n_in,
                              void* d_out, int out_size, void* d_ws, size_t ws_size,
                              hipStream_t stream)
{
    const float* hs       = (const float*)d_in[0];
    const float* w_kv_d   = (const float*)d_in[1];
    const float* w_q_d    = (const float*)d_in[2];
    const float* w_k_u    = (const float*)d_in[3];
    const float* w_q_u    = (const float*)d_in[4];
    const float* w_v_u    = (const float*)d_in[5];
    const float* w_rope_k = (const float*)d_in[6];
    const float* w_rope_q = (const float*)d_in[7];
    const float* w_o      = (const float*)d_in[8];
    float* out = (float*)d_out;

    char* p = (char*)d_ws;
    auto alloc = [&](size_t nelem) {
        __hip_bfloat16* r = (__hip_bfloat16*)p;
        p += nelem * sizeof(__hip_bfloat16);
        return r;
    };
    __hip_bfloat16* hsb  = alloc((size_t)BS * HID);        // 16 MB (reused as attn)
    __hip_bfloat16* qkvd = alloc((size_t)BS * 512);        // 4 MB
    __hip_bfloat16* WT1  = alloc((size_t)1536 * 2048);     // 6 MB
    __hip_bfloat16* WT2  = alloc((size_t)3072 * 256);      // 1.5 MB
    __hip_bfloat16* WT3  = alloc((size_t)2048 * 256);      // 1 MB
    __hip_bfloat16* WTo  = alloc((size_t)2048 * 2048);     // 8 MB
    __hip_bfloat16* Kbuf = alloc((size_t)BS * HID);        // 16 MB
    __hip_bfloat16* Qbuf = alloc((size_t)BS * HID);        // 16 MB
    __hip_bfloat16* Vtb  = alloc((size_t)HID * BS);        // 16 MB, [h*128+d][b*S+s]
    __hip_bfloat16* attn = hsb;   // hs dead after G1

    dim3 blk(256);

    // 0a. hs -> bf16
    convert_kernel<<<dim3((BS * HID / 8 + 255) / 256), blk, 0, stream>>>(
        hs, hsb, BS * HID / 8);
    // 0b. all weights: transpose + convert to bf16 W^T
    transpose_weights_kernel<<<dim3(8448), blk, 0, stream>>>(
        w_kv_d, w_q_d, w_rope_k, w_k_u, w_v_u, w_q_u, w_rope_q, w_o,
        WT1, WT2, WT3, WTo);

    // G1: [kv_d | q_d | krp] = hsb @ WT1^T  (N=1536, K=2048)
    gemm_bt_kernel<__hip_bfloat16><<<dim3(1536 / 128, BS / 128), blk, 0, stream>>>(
        hsb, 2048, WT1,
        qkvd, 512, 0, 0, 1.0f,
        Kbuf, 2048, 1, 64, 1.0f,
        512, 2048);
    // G2: [k_p | v] = kv_d @ WT2^T  (N=3072, K=256)
    gemm_bt_kernel<__hip_bfloat16><<<dim3(3072 / 128, BS / 128), blk, 0, stream>>>(
        qkvd, 512, WT2,
        Kbuf, 2048, 1, 0, 1.0f,
        Vtb, 0, 2, 0, 1.0f,
        1024, 256);
    // G3: [q_p | q_rope_pre] = q_d @ WT3^T  (N=2048, K=256)
    gemm_bt_kernel<__hip_bfloat16><<<dim3(2048 / 128, BS / 128), blk, 0, stream>>>(
        qkvd + 256, 512, WT3,
        Qbuf, 2048, 1, 0, 1.0f,
        Qbuf, 2048, 1, 64, 1.0f,
        1024, 256);
    // 4. RoPE in-place on K/Q rope halves
    rope_kernel<<<dim3((BS * NH * 32 + 255) / 256), blk, 0, stream>>>(Kbuf, Qbuf);
    // 5. flash attention v11 -> attn (8-wave paired blocks, K+V dbuf)
    flash_attn_kernel<<<dim3(8, NH, BB), dim3(512), 0, stream>>>(
        Qbuf, Kbuf, Vtb, attn);
    // G4: out = attn @ WTo^T (fp32 out)
    gemm_bt_kernel<float><<<dim3(2048 / 128, BS / 128), blk, 0, stream>>>(
        attn, 2048, WTo,
        out, 2048, 0, 0, 1.0f,
        out, 2048, 0, 0, 1.0f,
        2048, 2048);
}